// Round 1
// baseline (4941.563 us; speedup 1.0000x reference)
//
#include <hip/hip_runtime.h>

// ---------------------------------------------------------------------------
// SimpleGCNTanh on MI355X — round 1 baseline.
// Pipeline:
//   deg/dinv  (atomic count, rsqrt)
//   3x GCNConv: hw = h@W  (tiled fp32 GEMM; epilogue also writes agg = hw*dinv^2)
//               agg[dst] += hw[src]*dinv[src]*dinv[dst]  (per-edge atomics, wave/edge)
//               h = tanh(agg + b)
//   h2 = tanh(h@W2+b2), h3 = tanh(h2@W3+b3)  (tiled GEMM + fused bias/tanh)
//   per-edge: e = [h3[src], h3[dst]] -> d_out[E*6:], out = e@Wcls+bcls -> d_out[:E*6]
// Workspace layout (floats): dinv[N] | bufA[N*128] | bufB[N*128]  (~103 MB)
// ---------------------------------------------------------------------------

__global__ __launch_bounds__(256) void deg_init_kernel(float* __restrict__ deg, int n) {
    int i = blockIdx.x * 256 + threadIdx.x;
    if (i < n) deg[i] = 1.0f;  // self-loop
}

__global__ __launch_bounds__(256) void deg_count_kernel(float* __restrict__ deg,
                                                        const int* __restrict__ dst, int E) {
    int e = blockIdx.x * 256 + threadIdx.x;
    if (e < E) atomicAdd(&deg[dst[e]], 1.0f);
}

__global__ __launch_bounds__(256) void deg_finish_kernel(float* __restrict__ deg, int n) {
    int i = blockIdx.x * 256 + threadIdx.x;
    if (i < n) deg[i] = rsqrtf(deg[i]);  // deg -> dinv in place
}

// ---------------------------------------------------------------------------
// Tiled fp32 GEMM: Y = X[n,K] @ W[K,M]
// EPI 0: Y = XW               and Y2 = XW * dinv[row]^2   (GCN self-loop init)
// EPI 1: Y = tanh(XW + bias)
// Block: 256 threads, 4x4 register tile per thread, BK=32 k-chunks in LDS.
// ---------------------------------------------------------------------------
template <int K, int M, int EPI>
__global__ __launch_bounds__(256) void gemm_kernel(const float* __restrict__ X,
                                                   const float* __restrict__ W,
                                                   float* __restrict__ Y,
                                                   float* __restrict__ Y2,
                                                   const float* __restrict__ bias,
                                                   const float* __restrict__ dinv, int n) {
    constexpr int BK = 32;
    constexpr int TC = M / 4;      // threads along cols
    constexpr int TR = 256 / TC;   // threads along rows
    constexpr int R = TR * 4;      // rows per block

    __shared__ float xs[R * BK];
    __shared__ float ws[BK * M];

    const int t = threadIdx.x;
    const int tc = t % TC, tr = t / TC;
    const int c0 = tc * 4;
    const int r0 = tr * 4;
    const int row0 = blockIdx.x * R;

    float acc[4][4] = {};

    for (int k0 = 0; k0 < K; k0 += BK) {
        // stage X tile (R x BK), zero-fill out-of-range rows
        constexpr int XV = (R * BK) / (256 * 4);
#pragma unroll
        for (int i = 0; i < XV; ++i) {
            int idx = (t + i * 256) * 4;
            int rr = idx / BK, kk = idx % BK;
            int grow = row0 + rr;
            float4 v = make_float4(0.f, 0.f, 0.f, 0.f);
            if (grow < n) v = *(const float4*)&X[(size_t)grow * K + k0 + kk];
            *(float4*)&xs[idx] = v;
        }
        // stage W tile (BK x M)
        constexpr int WV = (BK * M) / (256 * 4);
#pragma unroll
        for (int i = 0; i < WV; ++i) {
            int idx = (t + i * 256) * 4;
            int kk = idx / M, mm = idx % M;
            *(float4*)&ws[idx] = *(const float4*)&W[(size_t)(k0 + kk) * M + mm];
        }
        __syncthreads();
#pragma unroll
        for (int kk = 0; kk < BK; kk += 4) {
            float4 xv[4], wv[4];
#pragma unroll
            for (int i = 0; i < 4; ++i) xv[i] = *(const float4*)&xs[(r0 + i) * BK + kk];
#pragma unroll
            for (int j = 0; j < 4; ++j) wv[j] = *(const float4*)&ws[(kk + j) * M + c0];
#pragma unroll
            for (int i = 0; i < 4; ++i) {
                const float* xp = (const float*)&xv[i];
#pragma unroll
                for (int j = 0; j < 4; ++j) {
                    const float xk = xp[j];
                    const float* wp = (const float*)&wv[j];
                    acc[i][0] += xk * wp[0];
                    acc[i][1] += xk * wp[1];
                    acc[i][2] += xk * wp[2];
                    acc[i][3] += xk * wp[3];
                }
            }
        }
        __syncthreads();
    }

#pragma unroll
    for (int i = 0; i < 4; ++i) {
        int grow = row0 + r0 + i;
        if (grow >= n) continue;
        float4 v = make_float4(acc[i][0], acc[i][1], acc[i][2], acc[i][3]);
        if (EPI == 0) {
            *(float4*)&Y[(size_t)grow * M + c0] = v;
            float di = dinv[grow];
            float d2 = di * di;
            float4 v2 = make_float4(v.x * d2, v.y * d2, v.z * d2, v.w * d2);
            *(float4*)&Y2[(size_t)grow * M + c0] = v2;
        } else {
            v.x = tanhf(v.x + bias[c0 + 0]);
            v.y = tanhf(v.y + bias[c0 + 1]);
            v.z = tanhf(v.z + bias[c0 + 2]);
            v.w = tanhf(v.w + bias[c0 + 3]);
            *(float4*)&Y[(size_t)grow * M + c0] = v;
        }
    }
}

// ---------------------------------------------------------------------------
// Per-edge scatter: agg[dst] += hw[src] * dinv[src]*dinv[dst].  One wave/edge,
// 64 lanes x float2 = 128 features. Coalesced 512B gather, atomic fp32 adds.
// ---------------------------------------------------------------------------
__global__ __launch_bounds__(256) void scatter_kernel(const float* __restrict__ hw,
                                                      float* __restrict__ agg,
                                                      const int* __restrict__ src,
                                                      const int* __restrict__ dst,
                                                      const float* __restrict__ dinv, int E) {
    int gid = blockIdx.x * 256 + threadIdx.x;
    int edge = gid >> 6;
    int lane = gid & 63;
    if (edge >= E) return;
    int s = src[edge];
    int d = dst[edge];
    float coef = dinv[s] * dinv[d];
    float2 v = *(const float2*)&hw[(size_t)s * 128 + lane * 2];
    atomicAdd(&agg[(size_t)d * 128 + lane * 2 + 0], v.x * coef);
    atomicAdd(&agg[(size_t)d * 128 + lane * 2 + 1], v.y * coef);
}

template <int M>
__global__ __launch_bounds__(256) void bias_tanh_kernel(float* __restrict__ h,
                                                        const float* __restrict__ b, int total) {
    int i = blockIdx.x * 256 + threadIdx.x;
    if (i < total) h[i] = tanhf(h[i] + b[i & (M - 1)]);
}

// ---------------------------------------------------------------------------
// Final per-edge kernel: e = concat(h3[src], h3[dst]) (write to e_out),
// out = e @ Wcls + bcls.  32 threads per edge, 2 e-columns per thread,
// shfl-xor reduction over the 32-lane half-wave for the 6-way dot.
// ---------------------------------------------------------------------------
__global__ __launch_bounds__(256) void edge_out_kernel(const float* __restrict__ h3,
                                                       const int* __restrict__ src,
                                                       const int* __restrict__ dst,
                                                       const float* __restrict__ Wcls,
                                                       const float* __restrict__ bcls,
                                                       float* __restrict__ out,
                                                       float* __restrict__ e_out, int E) {
    __shared__ float wcl[64 * 6];
    __shared__ float bcl[6];
    for (int i = threadIdx.x; i < 64 * 6; i += 256) wcl[i] = Wcls[i];
    if (threadIdx.x < 6) bcl[threadIdx.x] = bcls[threadIdx.x];
    __syncthreads();

    int gid = blockIdx.x * 256 + threadIdx.x;
    int edge = gid >> 5;
    int c = gid & 31;
    if (edge >= E) return;
    int s = src[edge];
    int d = dst[edge];
    float2 v;
    if (c < 16)
        v = *(const float2*)&h3[(size_t)s * 32 + c * 2];
    else
        v = *(const float2*)&h3[(size_t)d * 32 + (c - 16) * 2];
    *(float2*)&e_out[(size_t)edge * 64 + c * 2] = v;

    float p[6];
#pragma unroll
    for (int j = 0; j < 6; ++j)
        p[j] = v.x * wcl[(c * 2) * 6 + j] + v.y * wcl[(c * 2 + 1) * 6 + j];
#pragma unroll
    for (int m = 16; m >= 1; m >>= 1) {
#pragma unroll
        for (int j = 0; j < 6; ++j) p[j] += __shfl_xor(p[j], m, 64);
    }
    if (c == 0) {
#pragma unroll
        for (int j = 0; j < 6; ++j) out[(size_t)edge * 6 + j] = p[j] + bcl[j];
    }
}

// ---------------------------------------------------------------------------

static inline int cdiv(long long a, long long b) { return (int)((a + b - 1) / b); }

extern "C" void kernel_launch(void* const* d_in, const int* in_sizes, int n_in,
                              void* d_out, int out_size, void* d_ws, size_t ws_size,
                              hipStream_t stream) {
    const int N = in_sizes[0] / 128;
    const int E = in_sizes[1] / 2;

    const float* x = (const float*)d_in[0];
    const int* ei = (const int*)d_in[1];
    const int* srcp = ei;
    const int* dstp = ei + E;
    const float* W1 = (const float*)d_in[3];
    const float* b1 = (const float*)d_in[4];
    const float* Wc = (const float*)d_in[5];
    const float* bc = (const float*)d_in[6];
    const float* W2 = (const float*)d_in[7];
    const float* b2 = (const float*)d_in[8];
    const float* W3 = (const float*)d_in[9];
    const float* b3 = (const float*)d_in[10];
    const float* Wcls = (const float*)d_in[11];
    const float* bcls = (const float*)d_in[12];

    float* wsf = (float*)d_ws;
    float* dinv = wsf;                          // N
    float* bufA = wsf + N;                      // N*128
    float* bufB = bufA + (size_t)N * 128;       // N*128

    float* out = (float*)d_out;                 // E*6
    float* e_out = out + (size_t)E * 6;         // E*64

    // degree -> dinv
    deg_init_kernel<<<cdiv(N, 256), 256, 0, stream>>>(dinv, N);
    deg_count_kernel<<<cdiv(E, 256), 256, 0, stream>>>(dinv, dstp, E);
    deg_finish_kernel<<<cdiv(N, 256), 256, 0, stream>>>(dinv, N);

    // conv1: hw=x@W1 -> bufB ; agg init -> bufA ; scatter ; tanh(+b1)
    gemm_kernel<128, 128, 0><<<cdiv(N, 32), 256, 0, stream>>>(x, W1, bufB, bufA, nullptr, dinv, N);
    scatter_kernel<<<cdiv((long long)E * 64, 256), 256, 0, stream>>>(bufB, bufA, srcp, dstp, dinv, E);
    bias_tanh_kernel<128><<<cdiv((long long)N * 128, 256), 256, 0, stream>>>(bufA, b1, N * 128);

    // conv2, conv3
    for (int i = 0; i < 2; ++i) {
        gemm_kernel<128, 128, 0><<<cdiv(N, 32), 256, 0, stream>>>(bufA, Wc + (size_t)i * 128 * 128,
                                                                  bufB, bufA, nullptr, dinv, N);
        scatter_kernel<<<cdiv((long long)E * 64, 256), 256, 0, stream>>>(bufB, bufA, srcp, dstp,
                                                                         dinv, E);
        bias_tanh_kernel<128><<<cdiv((long long)N * 128, 256), 256, 0, stream>>>(bufA, bc + i * 128,
                                                                                 N * 128);
    }

    // h2 = tanh(h@W2+b2) -> bufB (N x 64)
    gemm_kernel<128, 64, 1><<<cdiv(N, 64), 256, 0, stream>>>(bufA, W2, bufB, nullptr, b2, nullptr, N);
    // h3 = tanh(h2@W3+b3) -> bufA (N x 32)
    gemm_kernel<64, 32, 1><<<cdiv(N, 128), 256, 0, stream>>>(bufB, W3, bufA, nullptr, b3, nullptr, N);

    // per-edge outputs
    edge_out_kernel<<<cdiv((long long)E * 32, 256), 256, 0, stream>>>(bufA, srcp, dstp, Wcls, bcls,
                                                                      out, e_out, E);
}